// Round 4
// baseline (246.087 us; speedup 1.0000x reference)
//
#include <hip/hip_runtime.h>

// PyramidROIAlign: out[b,n,py,px,c] = bilinear crop from the FPN level
// selected per-box by log2(sqrt(h*w)*sqrt(area)/224).
//
// v4b = v3 + two cache-policy fixes (v4 fixed: nontemporal store needs a
// native clang vector type, not HIP's float4 class):
//  (a) bijective XCD swizzle (8 XCDs): hardware round-robins blockIdx.x
//      across XCDs, so the 7 consecutive blocks of one box landed on 7
//      DIFFERENT per-XCD L2s. Remap so contiguous logical blocks (same
//      box, neighboring boxes) share one XCD's L2 -> cross-pool-row corner
//      re-reads become L2 hits.
//  (b) nontemporal output stores: 100 MB of write-once data no longer
//      evicts feature lines from L2/L3.
// Structure unchanged from v3: one 448-thread block (7 waves) per
// (box, pool-row); wave px = pool column; lane t = channels [4t,4t+4).

typedef float floatx4 __attribute__((ext_vector_type(4)));

__global__ __launch_bounds__(448) void roi_align_kernel(
    const float* __restrict__ boxes,   // (B,N,4) y1,x1,y2,x2
    const float* __restrict__ meta,    // (B,14); meta[4],meta[5] = img H,W
    const float* __restrict__ f2,      // (B,256,256,256)
    const float* __restrict__ f3,      // (B,128,128,256)
    const float* __restrict__ f4,      // (B, 64, 64,256)
    const float* __restrict__ f5,      // (B, 32, 32,256)
    float* __restrict__ out,           // (B,N,7,7,256)
    int N)
{
    const int C = 256;

    // ---- bijective XCD swizzle (m204): logical id 'bid' is contiguous
    // within each XCD regardless of gridDim%8 ----
    int orig = blockIdx.x;
    int nwg  = gridDim.x;
    int q = nwg >> 3, r = nwg & 7;
    int xcd  = orig & 7;
    int bid  = (xcd < r ? xcd * (q + 1) : r * (q + 1) + (xcd - r) * q)
             + (orig >> 3);

    int bn  = bid / 7;                  // box index: b*N + n
    int py  = bid - bn * 7;             // pool row
    int b   = bn / N;
    int px  = threadIdx.x >> 6;         // wave id 0..6 = pool column
    int lane = threadIdx.x & 63;        // 4 channels each

    // ---- per-box scalar setup (wave-uniform) ----
    float y1 = boxes[bn * 4 + 0];
    float x1 = boxes[bn * 4 + 1];
    float y2 = boxes[bn * 4 + 2];
    float x2 = boxes[bn * 4 + 3];
    float h = y2 - y1;
    float w = x2 - x1;

    // roi_level = clip(4 + round(log2(sqrt(h*w) / (224/sqrt(imgH*imgW)))), 2, 5)
    float area = meta[4] * meta[5];
    float lvl  = log2f(sqrtf(h * w) / (224.0f / sqrtf(area)));
    float rl   = 4.0f + rintf(lvl);          // rintf = half-to-even, matches jnp.round
    rl = fminf(fmaxf(rl, 2.0f), 5.0f);       // -inf (degenerate box) clamps to 2
    int level = (int)rl;

    const float* fm;
    int H;
    if (level == 2)      { fm = f2; H = 256; }
    else if (level == 3) { fm = f3; H = 128; }
    else if (level == 4) { fm = f4; H = 64;  }
    else                 { fm = f5; H = 32;  }
    int W = H;

    // ---- sample coordinates (match reference fp32 op order) ----
    float sy = (h * (float)(H - 1)) / 6.0f;
    float sx = (w * (float)(W - 1)) / 6.0f;
    float ys = y1 * (float)(H - 1) + (float)py * sy;
    float xs = x1 * (float)(W - 1) + (float)px * sx;
    float y0f = floorf(ys);
    float x0f = floorf(xs);
    int y0 = min(max((int)y0f, 0), H - 1);
    int yi = min(y0 + 1, H - 1);
    int x0 = min(max((int)x0f, 0), W - 1);
    int xi = min(x0 + 1, W - 1);
    float fy = ys - y0f;
    float fx = xs - x0f;

    size_t base = (size_t)b * H * W * C;
    const float4* ptl = (const float4*)(fm + base + ((size_t)y0 * W + x0) * C);
    const float4* ptr = (const float4*)(fm + base + ((size_t)y0 * W + xi) * C);
    const float4* pbl = (const float4*)(fm + base + ((size_t)yi * W + x0) * C);
    const float4* pbr = (const float4*)(fm + base + ((size_t)yi * W + xi) * C);

    float4 tl = ptl[lane];
    float4 tr = ptr[lane];
    float4 bl = pbl[lane];
    float4 br = pbr[lane];

    floatx4 o;
    {
        float top = tl.x + (tr.x - tl.x) * fx;
        float bot = bl.x + (br.x - bl.x) * fx;
        o.x = top + (bot - top) * fy;
    }
    {
        float top = tl.y + (tr.y - tl.y) * fx;
        float bot = bl.y + (br.y - bl.y) * fx;
        o.y = top + (bot - top) * fy;
    }
    {
        float top = tl.z + (tr.z - tl.z) * fx;
        float bot = bl.z + (br.z - bl.z) * fx;
        o.z = top + (bot - top) * fy;
    }
    {
        float top = tl.w + (tr.w - tl.w) * fx;
        float bot = bl.w + (br.w - bl.w) * fx;
        o.w = top + (bot - top) * fy;
    }

    floatx4* po = (floatx4*)(out + ((size_t)bn * 49 + (size_t)py * 7 + px) * C);
    __builtin_nontemporal_store(o, po + lane);   // write-once: keep out of L2/L3
}

extern "C" void kernel_launch(void* const* d_in, const int* in_sizes, int n_in,
                              void* d_out, int out_size, void* d_ws, size_t ws_size,
                              hipStream_t stream) {
    const float* boxes = (const float*)d_in[0];
    const float* meta  = (const float*)d_in[1];
    const float* f2    = (const float*)d_in[2];
    const float* f3    = (const float*)d_in[3];
    const float* f4    = (const float*)d_in[4];
    const float* f5    = (const float*)d_in[5];
    float* out = (float*)d_out;

    int B = in_sizes[1] / 14;            // image_meta is (B,14)
    int N = in_sizes[0] / (4 * B);       // boxes is (B,N,4)

    int grid = B * N * 7;                // one 7-wave block per (box, pool row)
    roi_align_kernel<<<grid, 448, 0, stream>>>(boxes, meta, f2, f3, f4, f5, out, N);
}